// Round 2
// baseline (544.006 us; speedup 1.0000x reference)
//
#include <hip/hip_runtime.h>
#include <hip/hip_fp16.h>

#define CH 256
#define HH 96
#define WW 160
#define HW (HH * WW) // 15360

typedef _Float16 half8 __attribute__((ext_vector_type(8)));
typedef float f32x4 __attribute__((ext_vector_type(4)));

__device__ inline unsigned pk2f(float a, float b) {
    return (unsigned)__half_as_ushort(__float2half(a)) |
           ((unsigned)__half_as_ushort(__float2half(b)) << 16);
}

// WG = 256 threads = 4 waves. Tile: (b, rows y0..y0+3, cols x0..x0+15).
// Wave wv owns output row y0+wv for all 9 dy. A (F) fragments live in
// registers for all 8 K-chunks; S staged in double-buffered LDS with
// conflict-free ds_write_b128 (each thread packs 8 channels of one column).
__global__ __launch_bounds__(256, 2)
void corr_mfma2(const float* __restrict__ Fp, const float* __restrict__ Sp,
                float* __restrict__ out) {
    // [buf][row*128 + jt*64 + qq*16 + nn] quads of 8 f16 channels : 48 KB
    __shared__ uint4 sS[2][12 * 128];

    const int bid = blockIdx.x;
    const int b   = bid & 7;       // batch-per-XCD swizzle for L2 locality
    const int rem = bid >> 3;      // 0..239
    const int y0  = (rem / 10) * 4;
    const int x0  = (rem % 10) * 16;

    const int t    = threadIdx.x;
    const int lane = t & 63;
    const int wv   = t >> 6;
    const int q    = lane >> 4;
    const int n    = lane & 15;

    const float* Fb = Fp + (size_t)b * CH * HW;
    const float* Sb = Sp + (size_t)b * CH * HW;

    // ---- A fragments (F) for all 8 chunks -> 32 VGPRs.
    // A[m=lane&15][k=q*8+j] = F[c0+q*8+j][y0+wv][x0+m]; every elem read once.
    half8 av[8];
    {
        const float* fp0 = Fb + (size_t)(q * 8) * HW + (y0 + wv) * WW + x0 + n;
#pragma unroll
        for (int ch = 0; ch < 8; ch++) {
            float f[8];
#pragma unroll
            for (int j = 0; j < 8; j++)
                f[j] = fp0[(size_t)(ch * 32 + j) * HW];
            half8 h;
#pragma unroll
            for (int j = 0; j < 8; j++) h[j] = (_Float16)f[j];
            av[ch] = h;
        }
    }

    // ---- S staging: 12 rows x 32 cols x 32 ch per chunk = 1536 quads,
    // 6 per thread. linear = i*256+t -> nn/qq/jt/row; write idx is
    // base + distinct-per-lane  => conflict-free ds_write_b128.
    auto issue = [&](int c0v, float (&pf)[6][8]) {
#pragma unroll
        for (int i = 0; i < 6; i++) {
            const int linear = i * 256 + t;
            const int nn  = linear & 15;
            const int qq  = (linear >> 4) & 3;
            const int jt  = (linear >> 6) & 1;
            const int row = linear >> 7;
            const int gx = x0 - 4 + jt * 16 + nn;
            const int gy = y0 - 4 + row;          // wave-uniform predicate
            const bool ok = ((unsigned)gy < HH) & ((unsigned)gx < WW);
            const float* p = Sb + ((long long)(c0v + qq * 8) * HW +
                                   (long long)gy * WW + gx);
#pragma unroll
            for (int j = 0; j < 8; j++)
                pf[i][j] = ok ? p[(size_t)j * HW] : 0.0f;
        }
    };
    auto commit = [&](uint4* buf, float (&pf)[6][8]) {
#pragma unroll
        for (int i = 0; i < 6; i++) {
            const int linear = i * 256 + t;
            const int nn  = linear & 15;
            const int qq  = (linear >> 4) & 3;
            const int jt  = (linear >> 6) & 1;
            const int row = linear >> 7;
            uint4 v;
            v.x = pk2f(pf[i][0], pf[i][1]);
            v.y = pk2f(pf[i][2], pf[i][3]);
            v.z = pk2f(pf[i][4], pf[i][5]);
            v.w = pk2f(pf[i][6], pf[i][7]);
            buf[row * 128 + jt * 64 + qq * 16 + nn] = v;
        }
    };

    f32x4 acc[9][2];
#pragma unroll
    for (int dy = 0; dy < 9; dy++) {
        f32x4 z = {0.f, 0.f, 0.f, 0.f};
        acc[dy][0] = z;
        acc[dy][1] = z;
    }

    {
        float pf[6][8];
        issue(0, pf);
        commit(sS[0], pf);
    }

#pragma unroll
    for (int ch = 0; ch < 8; ch++) {
        __syncthreads();
        const uint4* cur = sS[ch & 1];
        float pn[6][8];
        if (ch < 7) issue((ch + 1) * 32, pn);  // overlaps MFMA below
#pragma unroll
        for (int dy = 0; dy < 9; dy++) {
            const int row = wv + dy; // 0..11
            half8 b0 = *(const half8*)(cur + row * 128 + lane);
            half8 b1 = *(const half8*)(cur + row * 128 + 64 + lane);
            acc[dy][0] = __builtin_amdgcn_mfma_f32_16x16x32_f16(av[ch], b0, acc[dy][0], 0, 0, 0);
            acc[dy][1] = __builtin_amdgcn_mfma_f32_16x16x32_f16(av[ch], b1, acc[dy][1], 0, 0, 0);
        }
        if (ch < 7) commit((uint4*)sS[(ch + 1) & 1], pn);
    }

    // ---- epilogue: D row m=q*4+r, col n; dx+4 = jt*16 + n - m in [0,8].
    const int y = y0 + wv;
#pragma unroll
    for (int r = 0; r < 4; r++) {
        const int m = q * 4 + r;
#pragma unroll
        for (int jt = 0; jt < 2; jt++) {
            const int dxp = jt * 16 + n - m;
            if (dxp >= 0 && dxp <= 8) {
                float* p = out + ((size_t)(b * 81 + dxp) * HH + y) * WW + x0 + m;
#pragma unroll
                for (int dy = 0; dy < 9; dy++) {
                    p[(size_t)dy * 9 * HW] = acc[dy][jt][r] * (1.0f / 256.0f);
                }
            }
        }
    }
}

extern "C" void kernel_launch(void* const* d_in, const int* in_sizes, int n_in,
                              void* d_out, int out_size, void* d_ws, size_t ws_size,
                              hipStream_t stream) {
    const float* F = (const float*)d_in[0];
    const float* S = (const float*)d_in[1];
    float* o = (float*)d_out;
    corr_mfma2<<<dim3(1920), dim3(256), 0, stream>>>(F, S, o);
}

// Round 3
// 330.709 us; speedup vs baseline: 1.6450x; 1.6450x over previous
//
#include <hip/hip_runtime.h>
#include <hip/hip_fp16.h>

#define CH 256
#define HH 96
#define WW 160
#define HW (HH * WW) // 15360

typedef _Float16 half8 __attribute__((ext_vector_type(8)));
typedef float f32x4 __attribute__((ext_vector_type(4)));

__device__ inline unsigned pk2f(float a, float b) {
    return (unsigned)__half_as_ushort(__float2half(a)) |
           ((unsigned)__half_as_ushort(__float2half(b)) << 16);
}

// WG = 256 threads = 4 waves; tile (b, rows y0..y0+3, cols x0..x0+15).
// Single-buffered LDS (24.5 KB) -> 4 blocks/CU at VGPR<=128: latency hiding
// comes from 4 independent resident blocks, not intra-wave pipelining.
// S staging: thread owns a col-pair of 8-channel quads -> float2 global
// loads (512B/instr coalescing) + conflict-free ds_write_b128 pairs.
__global__ __launch_bounds__(256, 4)
void corr_v3(const float* __restrict__ Fp, const float* __restrict__ Sp,
             float* __restrict__ out) {
    __shared__ uint4 sS[12 * 128]; // [row12][jt2][qq4][nn16] : 24.5 KB

    const int bid = blockIdx.x;
    const int b   = bid & 7;       // batch-per-XCD swizzle
    const int rem = bid >> 3;      // 0..239
    const int y0  = (rem / 10) * 4;
    const int x0  = (rem % 10) * 16;

    const int t    = threadIdx.x;
    const int lane = t & 63;
    const int wv   = t >> 6;
    const int q    = lane >> 4;
    const int n    = lane & 15;

    const float* Fb = Fp + (size_t)b * CH * HW;
    const float* Sb = Sp + (size_t)b * CH * HW;

    // Per-thread S-staging geometry: 3 col-pair groups.
    // pair_id = i*256 + t -> np(0..7), qq(0..3), jt(0..1), row = i*4+wv.
    // Quad idx = row*128 + jt*64 + qq*16 + np*2  ==  row*128 + lane*2.
    const int np = lane & 7;
    const int qq = (lane >> 3) & 3;
    const int jt = (lane >> 5) & 1;
    const int gx = x0 - 4 + jt * 16 + np * 2;
    const bool xok = (gx >= 0) & (gx + 1 < WW);

    f32x4 acc[9][2];
#pragma unroll
    for (int dy = 0; dy < 9; dy++) {
        f32x4 z = {0.f, 0.f, 0.f, 0.f};
        acc[dy][0] = z;
        acc[dy][1] = z;
    }

    for (int ch = 0; ch < 8; ch++) {
        const int c0 = ch * 32;

        // ---- A fragment gather for this chunk (8 dword loads, in flight
        // across the pack + barrier below). Always in bounds.
        const float* fp0 = Fb + (size_t)(c0 + q * 8) * HW + (y0 + wv) * WW + x0 + n;
        float fa[8];
#pragma unroll
        for (int j = 0; j < 8; j++) fa[j] = fp0[(size_t)j * HW];

        // ---- S loads + pack: 3 groups x 8 float2 -> 6 packed quads.
        uint4 pk[3][2];
#pragma unroll
        for (int i = 0; i < 3; i++) {
            const int row = i * 4 + wv;
            const int gy  = y0 - 4 + row;
            const bool ok = ((unsigned)gy < HH) & xok;
            // fault-safe: clamp offset to 0 when OOB, zero-select after.
            const size_t off = ok ? ((size_t)(c0 + qq * 8) * HW +
                                     (size_t)gy * WW + gx) : 0;
            const float2* p2 = (const float2*)(Sb + off);
            float2 ld[8];
#pragma unroll
            for (int j = 0; j < 8; j++) {
                float2 v = p2[(size_t)j * (HW / 2)];
                ld[j].x = ok ? v.x : 0.0f;
                ld[j].y = ok ? v.y : 0.0f;
            }
            pk[i][0].x = pk2f(ld[0].x, ld[1].x);
            pk[i][0].y = pk2f(ld[2].x, ld[3].x);
            pk[i][0].z = pk2f(ld[4].x, ld[5].x);
            pk[i][0].w = pk2f(ld[6].x, ld[7].x);
            pk[i][1].x = pk2f(ld[0].y, ld[1].y);
            pk[i][1].y = pk2f(ld[2].y, ld[3].y);
            pk[i][1].z = pk2f(ld[4].y, ld[5].y);
            pk[i][1].w = pk2f(ld[6].y, ld[7].y);
        }

        half8 av;
#pragma unroll
        for (int j = 0; j < 8; j++) av[j] = (_Float16)fa[j];

        __syncthreads();   // all waves done reading previous chunk
#pragma unroll
        for (int i = 0; i < 3; i++) {
            uint4* dst = &sS[(i * 4 + wv) * 128 + lane * 2];
            dst[0] = pk[i][0];
            dst[1] = pk[i][1];
        }
        __syncthreads();   // staged chunk visible

        // ---- MFMA: 9 dy x 2 jt, conflict-free b128 fragment reads.
#pragma unroll
        for (int dy = 0; dy < 9; dy++) {
            const int row = wv + dy; // 0..11
            half8 b0 = *(const half8*)(sS + row * 128 + lane);
            half8 b1 = *(const half8*)(sS + row * 128 + 64 + lane);
            acc[dy][0] = __builtin_amdgcn_mfma_f32_16x16x32_f16(av, b0, acc[dy][0], 0, 0, 0);
            acc[dy][1] = __builtin_amdgcn_mfma_f32_16x16x32_f16(av, b1, acc[dy][1], 0, 0, 0);
        }
    }

    // ---- epilogue: D row m=q*4+r, col n; dx+4 = jt*16 + n - m in [0,8].
    const int y = y0 + wv;
#pragma unroll
    for (int r = 0; r < 4; r++) {
        const int m = q * 4 + r;
#pragma unroll
        for (int jtt = 0; jtt < 2; jtt++) {
            const int dxp = jtt * 16 + n - m;
            if (dxp >= 0 && dxp <= 8) {
                float* p = out + ((size_t)(b * 81 + dxp) * HH + y) * WW + x0 + m;
#pragma unroll
                for (int dy = 0; dy < 9; dy++) {
                    p[(size_t)dy * 9 * HW] = acc[dy][jtt][r] * (1.0f / 256.0f);
                }
            }
        }
    }
}

extern "C" void kernel_launch(void* const* d_in, const int* in_sizes, int n_in,
                              void* d_out, int out_size, void* d_ws, size_t ws_size,
                              hipStream_t stream) {
    const float* F = (const float*)d_in[0];
    const float* S = (const float*)d_in[1];
    float* o = (float*)d_out;
    corr_v3<<<dim3(1920), dim3(256), 0, stream>>>(F, S, o);
}

// Round 4
// 324.941 us; speedup vs baseline: 1.6742x; 1.0178x over previous
//
#include <hip/hip_runtime.h>
#include <hip/hip_fp16.h>

#define CH 256
#define HH 96
#define WW 160
#define HW (HH * WW) // 15360

typedef _Float16 half8 __attribute__((ext_vector_type(8)));
typedef float f32x4 __attribute__((ext_vector_type(4)));

__device__ inline unsigned pk2f(float a, float b) {
    return (unsigned)__half_as_ushort(__float2half(a)) |
           ((unsigned)__half_as_ushort(__float2half(b)) << 16);
}

// WG = 256 threads = 4 waves; tile (b, rows y0..y0+3, cols x0..x0+15).
// Software pipeline: raw global loads for chunk ch+1 are issued after the
// LDS commit of chunk ch and FIRST USED (select/cvt/pack) after the next
// barrier -- so the vmcnt wait lands one MFMA-section downstream of issue.
// rawS/rawF stay live across the MFMA section (expect VGPR ~150).
__global__ __launch_bounds__(256, 3)
void corr_v4(const float* __restrict__ Fp, const float* __restrict__ Sp,
             float* __restrict__ out) {
    __shared__ uint4 sS[12 * 128]; // [row12][jt2][qq4][nn16] : 24.5 KB

    const int bid = blockIdx.x;
    const int b   = bid & 7;       // batch-per-XCD swizzle
    const int rem = bid >> 3;      // 0..239
    const int y0  = (rem / 10) * 4;
    const int x0  = (rem % 10) * 16;

    const int t    = threadIdx.x;
    const int lane = t & 63;
    const int wv   = t >> 6;
    const int q    = lane >> 4;
    const int n    = lane & 15;

    const float* Fb = Fp + (size_t)b * CH * HW;
    const float* Sb = Sp + (size_t)b * CH * HW;

    // ---- chunk-invariant addressing (advance by 32 planes per chunk)
    const int np = lane & 7;
    const int qq = (lane >> 3) & 3;
    const int jt = (lane >> 5) & 1;
    const int gx = x0 - 4 + jt * 16 + np * 2;
    const bool xok = (gx >= 0) & (gx + 1 < WW);

    bool okv[3];
    const float2* pS[3];
#pragma unroll
    for (int i = 0; i < 3; i++) {
        const int row = i * 4 + wv;
        const int gy  = y0 - 4 + row;
        okv[i] = ((unsigned)gy < HH) & xok;
        const size_t off = okv[i] ? ((size_t)(qq * 8) * HW +
                                     (size_t)gy * WW + gx) : 0;
        pS[i] = (const float2*)(Sb + off);
    }
    const float* pF = Fb + (size_t)(q * 8) * HW + (y0 + wv) * WW + x0 + n;

    // ---- raw prefetch registers (live across MFMA section)
    float2 rawS[3][8]; // 48 VGPRs
    float  rawF[8];    //  8 VGPRs

    auto load_raw = [&]() {
#pragma unroll
        for (int i = 0; i < 3; i++)
#pragma unroll
            for (int j = 0; j < 8; j++)
                rawS[i][j] = pS[i][(size_t)j * (HW / 2)];
#pragma unroll
        for (int j = 0; j < 8; j++)
            rawF[j] = pF[(size_t)j * HW];
#pragma unroll
        for (int i = 0; i < 3; i++) pS[i] += (size_t)16 * HW; // 32 planes
        pF += (size_t)32 * HW;
    };

    f32x4 acc[9][2];
#pragma unroll
    for (int dy = 0; dy < 9; dy++) {
        f32x4 z = {0.f, 0.f, 0.f, 0.f};
        acc[dy][0] = z;
        acc[dy][1] = z;
    }

    load_raw(); // chunk 0 in flight

#pragma unroll 1
    for (int ch = 0; ch < 8; ch++) {
        __syncthreads();   // all waves done reading previous chunk's LDS

        // ---- pack & commit current chunk (first use of raw regs => the
        // vmcnt wait for loads issued last iteration lands here)
        half8 av;
#pragma unroll
        for (int j = 0; j < 8; j++) av[j] = (_Float16)rawF[j];
#pragma unroll
        for (int i = 0; i < 3; i++) {
            float2 ld[8];
#pragma unroll
            for (int j = 0; j < 8; j++) {
                ld[j].x = okv[i] ? rawS[i][j].x : 0.0f;
                ld[j].y = okv[i] ? rawS[i][j].y : 0.0f;
            }
            uint4 v0, v1;
            v0.x = pk2f(ld[0].x, ld[1].x);
            v0.y = pk2f(ld[2].x, ld[3].x);
            v0.z = pk2f(ld[4].x, ld[5].x);
            v0.w = pk2f(ld[6].x, ld[7].x);
            v1.x = pk2f(ld[0].y, ld[1].y);
            v1.y = pk2f(ld[2].y, ld[3].y);
            v1.z = pk2f(ld[4].y, ld[5].y);
            v1.w = pk2f(ld[6].y, ld[7].y);
            uint4* dst = &sS[(i * 4 + wv) * 128 + lane * 2];
            dst[0] = v0;
            dst[1] = v1;
        }
        __syncthreads();   // staged chunk visible

        // ---- issue next chunk's raw loads: no consumer until after the
        // next barrier -> they overlap the MFMA section below.
        if (ch < 7) load_raw();

        // ---- MFMA: 9 dy x 2 jt, conflict-free b128 fragment reads.
#pragma unroll
        for (int dy = 0; dy < 9; dy++) {
            const int row = wv + dy; // 0..11
            half8 b0 = *(const half8*)(sS + row * 128 + lane);
            half8 b1 = *(const half8*)(sS + row * 128 + 64 + lane);
            acc[dy][0] = __builtin_amdgcn_mfma_f32_16x16x32_f16(av, b0, acc[dy][0], 0, 0, 0);
            acc[dy][1] = __builtin_amdgcn_mfma_f32_16x16x32_f16(av, b1, acc[dy][1], 0, 0, 0);
        }
    }

    // ---- epilogue: D row m=q*4+r, col n; dx+4 = jt*16 + n - m in [0,8].
    const int y = y0 + wv;
#pragma unroll
    for (int r = 0; r < 4; r++) {
        const int m = q * 4 + r;
#pragma unroll
        for (int jtt = 0; jtt < 2; jtt++) {
            const int dxp = jtt * 16 + n - m;
            if (dxp >= 0 && dxp <= 8) {
                float* p = out + ((size_t)(b * 81 + dxp) * HH + y) * WW + x0 + m;
#pragma unroll
                for (int dy = 0; dy < 9; dy++) {
                    p[(size_t)dy * 9 * HW] = acc[dy][jtt][r] * (1.0f / 256.0f);
                }
            }
        }
    }
}

extern "C" void kernel_launch(void* const* d_in, const int* in_sizes, int n_in,
                              void* d_out, int out_size, void* d_ws, size_t ws_size,
                              hipStream_t stream) {
    const float* F = (const float*)d_in[0];
    const float* S = (const float*)d_in[1];
    float* o = (float*)d_out;
    corr_v4<<<dim3(1920), dim3(256), 0, stream>>>(F, S, o);
}